// Round 2
// baseline (168.717 us; speedup 1.0000x reference)
//
#include <hip/hip_runtime.h>

// TT-linear: y = x[16384,784] @ W[784,512] + bias; out = softmax(relu(y), axis=1)
// W materialized from TT cores (cheap), packed bf16 in MFMA B-fragment layout.
//
// ws layout (bytes):
//   [0,       1605632)  T123 : 401408 f32  [ijk(196)][pqe(128)][t(16)]
//   [1605632, 2424832)  Wp   : 409600 bf16 [((tn*25+tk)*64+lane)*8+j]
//                              = W[k=tk*32+(lane>>4)*8+j][n=tn*16+(lane&15)]

typedef __attribute__((ext_vector_type(8))) short short8;
typedef __attribute__((ext_vector_type(4))) float floatx4;

#define T123_OFF 0
#define WP_OFF   1605632

__device__ __forceinline__ unsigned int pack2_bf16(float a, float b) {
    unsigned int ua = __float_as_uint(a);
    unsigned int ub = __float_as_uint(b);
    return ((ub + 0x8000u) & 0xFFFF0000u) | ((ua + 0x8000u) >> 16);
}

// ---------- prep A (fused): t12 in LDS, then T123[ijk][pqe][t] ----------
// grid 1568 x 256; block covers 256 consecutive t123 elems => fixed ijk (and ij)
__global__ void prep_t123(const float* __restrict__ c1, const float* __restrict__ c2,
                          const float* __restrict__ c3, float* __restrict__ t123) {
    __shared__ float t12s[320];                 // [pq(16)][s(20)] for this block's ij
    const int tid = threadIdx.x;
    const int ijk = blockIdx.x >> 3;            // 196 values
    const int k3  = ijk % 7;
    const int ij  = ijk / 7;
    const int i   = ij >> 2, j2 = ij & 3;

    for (int e = tid; e < 320; e += 256) {
        int s  = e % 20;
        int pq = e / 20;
        int p = pq >> 2, q = pq & 3;
        float acc = 0.f;
        #pragma unroll
        for (int r = 0; r < 20; ++r)
            acc += c1[i * 80 + p * 20 + r] * c2[r * 320 + j2 * 80 + q * 20 + s];
        t12s[e] = acc;
    }
    __syncthreads();

    const int li  = (blockIdx.x & 7) * 256 + tid;   // 0..2047 within ijk
    const int t   = li & 15;
    const int pqe = li >> 4;
    const int e3  = pqe & 7;
    const int pq  = pqe >> 3;
    float acc = 0.f;
    const float* tp = t12s + pq * 20;
    const float* cp = c3 + k3 * 128 + e3 * 16 + t;
    #pragma unroll
    for (int s = 0; s < 20; ++s)
        acc += tp[s] * cp[s * 896];
    t123[(size_t)ijk * 2048 + li] = acc;
}

// ---------- prep B: W bf16, packed in B-fragment layout, K padded to 800 ----------
__global__ void prep_wp(const float* __restrict__ t123, const float* __restrict__ c4,
                        short* __restrict__ wp) {
    int idx = blockIdx.x * 256 + threadIdx.x;
    if (idx >= 409600) return;
    int j    = idx & 7;
    int lane = (idx >> 3) & 63;
    int tkt  = idx >> 9;
    int tk = tkt % 25;
    int tn = tkt / 25;
    int k = tk * 32 + (lane >> 4) * 8 + j;
    int n = tn * 16 + (lane & 15);
    float v = 0.f;
    if (k < 784) {
        int l  = k & 3;
        int k3 = (k >> 2) % 7;
        int ij = k / 28;
        int f4 = n & 3;
        int e  = (n >> 2) & 7;
        int q  = (n >> 5) & 3;
        int p  = n >> 7;
        int ijk = ij * 7 + k3;
        int pqe = p * 32 + q * 8 + e;
        const float* tp = t123 + (size_t)(ijk * 128 + pqe) * 16;
        const float* cp = c4 + l * 4 + f4;
        float a = 0.f;
        #pragma unroll
        for (int t = 0; t < 16; ++t)
            a += tp[t] * cp[t * 16];
        v = a;
    }
    unsigned int u = __float_as_uint(v);
    wp[idx] = (short)(((u + 0x7FFFu + ((u >> 16) & 1)) >> 16) & 0xFFFF);
}

// ---------- main GEMM + bias + relu + softmax ----------
// grid 1024 (16 rows each), block 512 = 8 waves; wave w owns cols [w*64, w*64+64)
// Barrier-free K-loop with 1-deep register prefetch; ~24 waves/CU for latency hiding.
__global__ __launch_bounds__(512, 4) void tt_gemm(const float* __restrict__ x,
                                                  const short* __restrict__ wp,
                                                  const float* __restrict__ bias,
                                                  float* __restrict__ out) {
    const int tid  = threadIdx.x;
    const int w    = tid >> 6;        // wave index = 64-col strip
    const int lane = tid & 63;
    const int quad = lane >> 4;
    const int lid  = lane & 15;
    const int m_base = blockIdx.x * 16;

    const float* xrow = x + (size_t)(m_base + lid) * 784;
    const short* wpw  = wp + (size_t)w * 4 * 25 * 512 + (lane << 3);

    floatx4 acc[4];
    #pragma unroll
    for (int nt = 0; nt < 4; ++nt) acc[nt] = floatx4{0.f, 0.f, 0.f, 0.f};

    auto loadA = [&](int tk) -> short8 {
        const int kk = tk * 32 + quad * 8;
        floatx4 v0 = floatx4{0.f, 0.f, 0.f, 0.f};
        floatx4 v1 = floatx4{0.f, 0.f, 0.f, 0.f};
        if (kk < 784) {                      // zero-padded tail; also avoids OOB on last row
            const floatx4* p = (const floatx4*)(xrow + kk);
            v0 = p[0];
            v1 = p[1];
        }
        union { short8 s; unsigned int u[4]; } af;
        af.u[0] = pack2_bf16(v0.x, v0.y);
        af.u[1] = pack2_bf16(v0.z, v0.w);
        af.u[2] = pack2_bf16(v1.x, v1.y);
        af.u[3] = pack2_bf16(v1.z, v1.w);
        return af.s;
    };
    auto loadB = [&](int nt, int tk) -> short8 {
        return *(const short8*)(wpw + (size_t)(nt * 25 + tk) * 512);
    };

    short8 aC = loadA(0);
    short8 bC0 = loadB(0, 0), bC1 = loadB(1, 0), bC2 = loadB(2, 0), bC3 = loadB(3, 0);

    #pragma unroll 1
    for (int tk = 0; tk < 25; ++tk) {
        const int tkn = (tk < 24) ? tk + 1 : 0;   // last iter: dummy refetch of tile 0
        short8 aN  = loadA(tkn);
        short8 bN0 = loadB(0, tkn);
        short8 bN1 = loadB(1, tkn);
        short8 bN2 = loadB(2, tkn);
        short8 bN3 = loadB(3, tkn);

        acc[0] = __builtin_amdgcn_mfma_f32_16x16x32_bf16(aC, bC0, acc[0], 0, 0, 0);
        acc[1] = __builtin_amdgcn_mfma_f32_16x16x32_bf16(aC, bC1, acc[1], 0, 0, 0);
        acc[2] = __builtin_amdgcn_mfma_f32_16x16x32_bf16(aC, bC2, acc[2], 0, 0, 0);
        acc[3] = __builtin_amdgcn_mfma_f32_16x16x32_bf16(aC, bC3, acc[3], 0, 0, 0);

        aC = aN; bC0 = bN0; bC1 = bN1; bC2 = bN2; bC3 = bN3;
    }

    // ---- epilogue: bias + relu + exp, row sums, softmax scale, store ----
    __shared__ float part[8][16];

    float bias_v[4];
    #pragma unroll
    for (int nt = 0; nt < 4; ++nt)
        bias_v[nt] = bias[w * 64 + nt * 16 + lid];

    #pragma unroll
    for (int reg = 0; reg < 4; ++reg) {
        float s = 0.f;
        #pragma unroll
        for (int nt = 0; nt < 4; ++nt) {
            float v = acc[nt][reg] + bias_v[nt];
            v = fmaxf(v, 0.f);
            float e = __expf(v);
            acc[nt][reg] = e;
            s += e;
        }
        // reduce across the 16 lanes of this quad (same output row)
        s += __shfl_xor(s, 1, 64);
        s += __shfl_xor(s, 2, 64);
        s += __shfl_xor(s, 4, 64);
        s += __shfl_xor(s, 8, 64);
        if (lid == 0) part[w][quad * 4 + reg] = s;
    }
    __syncthreads();

    #pragma unroll
    for (int reg = 0; reg < 4; ++reg) {
        const int rl = quad * 4 + reg;
        float tot = 0.f;
        #pragma unroll
        for (int ww = 0; ww < 8; ++ww) tot += part[ww][rl];
        const float inv = 1.0f / tot;
        const size_t row_g = m_base + rl;
        #pragma unroll
        for (int nt = 0; nt < 4; ++nt)
            out[row_g * 512 + w * 64 + nt * 16 + lid] = acc[nt][reg] * inv;
    }
}

extern "C" void kernel_launch(void* const* d_in, const int* in_sizes, int n_in,
                              void* d_out, int out_size, void* d_ws, size_t ws_size,
                              hipStream_t stream) {
    const float* x    = (const float*)d_in[0];
    const float* c1   = (const float*)d_in[1];
    const float* c2   = (const float*)d_in[2];
    const float* c3   = (const float*)d_in[3];
    const float* c4   = (const float*)d_in[4];
    const float* bias = (const float*)d_in[5];
    float* out = (float*)d_out;

    char* ws = (char*)d_ws;
    float* t123 = (float*)(ws + T123_OFF);
    short* wp   = (short*)(ws + WP_OFF);

    prep_t123<<<1568, 256, 0, stream>>>(c1, c2, c3, t123);
    prep_wp  <<<1600, 256, 0, stream>>>(t123, c4, wp);
    tt_gemm  <<<1024, 512, 0, stream>>>(x, wp, bias, out);
}

// Round 3
// 148.494 us; speedup vs baseline: 1.1362x; 1.1362x over previous
//
#include <hip/hip_runtime.h>

// TT-linear: y = x[16384,784] @ W[784,512] + bias; out = softmax(relu(y), axis=1)
// prep_all: build W (bf16, MFMA B-fragment layout) from TT cores in ONE kernel.
// tt_gemm : A staged in LDS (bf16, frag-ordered), B ping-pong from L2, 8 MFMA/iter/wave.
//
// ws layout: [0, 819200) Wp bf16, idx = ((tn*25+tk)*64 + lane)*8 + j
//            = W[k=tk*32+quad*8+j][n=tn*16+lid]   (lane = quad*16+lid)

typedef __attribute__((ext_vector_type(8))) short short8;
typedef __attribute__((ext_vector_type(4))) float floatx4;

__device__ __forceinline__ unsigned int pack2_bf16(float a, float b) {
    unsigned int ua = __float_as_uint(a);
    unsigned int ub = __float_as_uint(b);
    return ((ub + 0x8000u) & 0xFFFF0000u) | ((ua + 0x8000u) >> 16);
}

__device__ __forceinline__ short f32_to_bf16_rne(float v) {
    unsigned int u = __float_as_uint(v);
    return (short)(((u + 0x7FFFu + ((u >> 16) & 1)) >> 16) & 0xFFFF);
}

// ---------- fused prep: t12 -> t123 -> wp, all intermediates in LDS ----------
// grid 29 x 256. Blocks 0..27: one ij (28 k-values x 512 n). Block 28: zero K-pad.
__global__ void prep_all(const float* __restrict__ c1, const float* __restrict__ c2,
                         const float* __restrict__ c3, const float* __restrict__ c4,
                         short* __restrict__ wp) {
    const int tid = threadIdx.x;
    const int blk = blockIdx.x;
    if (blk == 28) {                       // zero wp for k in [784,800)
        for (int e = tid; e < 8192; e += 256) {
            int j   = e & 7;
            int lid = (e >> 3) & 15;
            int q2  = (e >> 7) & 1;
            int tn  = e >> 8;
            wp[(((tn * 25 + 24) * 64 + (2 + q2) * 16 + lid) << 3) + j] = 0;
        }
        return;
    }
    __shared__ float t12s[320];            // [pq(16)][s(20)]
    __shared__ float t123s[7 * 2048];      // [k3(7)][pqe(128)][t(16)]
    __shared__ float c4s[256];             // [t(16)][l(4)][f4(4)]
    const int ij = blk;
    const int i = ij >> 2, j2 = ij & 3;

    if (tid < 256) c4s[tid] = c4[tid];
    for (int e = tid; e < 320; e += 256) {
        int s = e % 20, pq = e / 20;
        int p = pq >> 2, q = pq & 3;
        float acc = 0.f;
        #pragma unroll
        for (int r = 0; r < 20; ++r)
            acc += c1[i * 80 + p * 20 + r] * c2[r * 320 + j2 * 80 + q * 20 + s];
        t12s[e] = acc;
    }
    __syncthreads();

    for (int e = tid; e < 14336; e += 256) {
        int k3 = e >> 11, li = e & 2047;
        int t = li & 15, pqe = li >> 4;
        int e3 = pqe & 7, pq = pqe >> 3;
        float acc = 0.f;
        const float* tp = t12s + pq * 20;
        const float* cp = c3 + k3 * 128 + e3 * 16 + t;
        #pragma unroll
        for (int s = 0; s < 20; ++s) acc += tp[s] * cp[s * 896];
        t123s[e] = acc;
    }
    __syncthreads();

    for (int e = tid; e < 28 * 512; e += 256) {
        int kl = e >> 9, n = e & 511;
        int k  = ij * 28 + kl;
        int k3 = kl >> 2, l = kl & 3;
        int f4 = n & 3, e3 = (n >> 2) & 7, q = (n >> 5) & 3, p = n >> 7;
        int pqe = p * 32 + q * 8 + e3;
        const float* tp = t123s + k3 * 2048 + pqe * 16;
        const float* cq = c4s + l * 4 + f4;
        float a = 0.f;
        #pragma unroll
        for (int t = 0; t < 16; ++t) a += tp[t] * cq[t * 16];
        int tk = k >> 5, quad = (k >> 3) & 3, j = k & 7;
        int tn = n >> 4, lid = n & 15;
        wp[(((tn * 25 + tk) * 64 + quad * 16 + lid) << 3) + j] = f32_to_bf16_rne(a);
    }
}

// ---------- main GEMM + bias + relu + softmax ----------
// grid 512 (32 rows each), block 512 = 8 waves; wave w owns cols [w*64, w*64+64).
// A in LDS (staged once, bf16, frag order: chunk = tk*128 + mt*64 + lane).
// B ping-pong registers from L2; fully unrolled K-loop, no register copies.
__global__ __launch_bounds__(512, 4) void tt_gemm(const float* __restrict__ x,
                                                  const short* __restrict__ wp,
                                                  const float* __restrict__ bias,
                                                  float* __restrict__ out) {
    __shared__ __align__(16) short s_a[3200 * 8];   // 51.2 KB
    __shared__ float part[8][32];

    const int tid  = threadIdx.x;
    const int w    = tid >> 6;
    const int lane = tid & 63;
    const int quad = lane >> 4;
    const int lid  = lane & 15;
    const int m_base = blockIdx.x * 32;

    // ---- stage A: fp32 -> bf16 into LDS, chunk-addr a = tk*128 + mt*64 + lane ----
    for (int a = tid; a < 3200; a += 512) {
        const int row = ((a >> 6) & 1) * 16 + (a & 15);          // mt*16 + lid
        const int kch = (a >> 7) * 4 + ((a >> 4) & 3);           // tk*4 + quad
        const int kc  = kch * 8;
        floatx4 v0 = {0.f, 0.f, 0.f, 0.f}, v1 = {0.f, 0.f, 0.f, 0.f};
        if (kc < 784) {
            const floatx4* p = (const floatx4*)(x + (size_t)(m_base + row) * 784 + kc);
            v0 = p[0]; v1 = p[1];
        }
        union { short8 s; unsigned int u[4]; } af;
        af.u[0] = pack2_bf16(v0.x, v0.y);
        af.u[1] = pack2_bf16(v0.z, v0.w);
        af.u[2] = pack2_bf16(v1.x, v1.y);
        af.u[3] = pack2_bf16(v1.z, v1.w);
        *(short8*)&s_a[a * 8] = af.s;
    }
    __syncthreads();

    const short* sa  = s_a + lane * 8;
    const short* wpw = wp + ((size_t)(w * 4) * 25 * 64 + lane) * 8;   // tn = w*4 + nt

    floatx4 acc[2][4];
    #pragma unroll
    for (int mt = 0; mt < 2; ++mt)
        #pragma unroll
        for (int nt = 0; nt < 4; ++nt)
            acc[mt][nt] = floatx4{0.f, 0.f, 0.f, 0.f};

    short8 a_f[2][2], b_f[2][4];
    a_f[0][0] = *(const short8*)(sa);
    a_f[0][1] = *(const short8*)(sa + 64 * 8);
    #pragma unroll
    for (int nt = 0; nt < 4; ++nt)
        b_f[0][nt] = *(const short8*)(wpw + (size_t)(nt * 25) * 64 * 8);

    #pragma unroll
    for (int tk = 0; tk < 25; ++tk) {
        const int cur = tk & 1, nxt = cur ^ 1;
        if (tk < 24) {
            const short* sa2 = sa + (size_t)(tk + 1) * 128 * 8;
            a_f[nxt][0] = *(const short8*)(sa2);
            a_f[nxt][1] = *(const short8*)(sa2 + 64 * 8);
            #pragma unroll
            for (int nt = 0; nt < 4; ++nt)
                b_f[nxt][nt] = *(const short8*)(wpw + (size_t)(nt * 25 + tk + 1) * 64 * 8);
        }
        #pragma unroll
        for (int nt = 0; nt < 4; ++nt) {
            acc[0][nt] = __builtin_amdgcn_mfma_f32_16x16x32_bf16(a_f[cur][0], b_f[cur][nt], acc[0][nt], 0, 0, 0);
            acc[1][nt] = __builtin_amdgcn_mfma_f32_16x16x32_bf16(a_f[cur][1], b_f[cur][nt], acc[1][nt], 0, 0, 0);
        }
    }

    // ---- epilogue: bias + relu + exp, row sums across 8 waves, scale, store ----
    float bias_v[4];
    #pragma unroll
    for (int nt = 0; nt < 4; ++nt)
        bias_v[nt] = bias[w * 64 + nt * 16 + lid];

    #pragma unroll
    for (int mt = 0; mt < 2; ++mt) {
        #pragma unroll
        for (int reg = 0; reg < 4; ++reg) {
            float s = 0.f;
            #pragma unroll
            for (int nt = 0; nt < 4; ++nt) {
                float v = acc[mt][nt][reg] + bias_v[nt];
                v = fmaxf(v, 0.f);
                float e = __expf(v);
                acc[mt][nt][reg] = e;
                s += e;
            }
            s += __shfl_xor(s, 1, 64);
            s += __shfl_xor(s, 2, 64);
            s += __shfl_xor(s, 4, 64);
            s += __shfl_xor(s, 8, 64);
            if (lid == 0) part[w][mt * 16 + quad * 4 + reg] = s;
        }
    }
    __syncthreads();

    #pragma unroll
    for (int mt = 0; mt < 2; ++mt) {
        #pragma unroll
        for (int reg = 0; reg < 4; ++reg) {
            const int row = mt * 16 + quad * 4 + reg;
            float tot = 0.f;
            #pragma unroll
            for (int ww = 0; ww < 8; ++ww) tot += part[ww][row];
            const float inv = 1.0f / tot;
            #pragma unroll
            for (int nt = 0; nt < 4; ++nt)
                out[(size_t)(m_base + row) * 512 + w * 64 + nt * 16 + lid] = acc[mt][nt][reg] * inv;
        }
    }
}

extern "C" void kernel_launch(void* const* d_in, const int* in_sizes, int n_in,
                              void* d_out, int out_size, void* d_ws, size_t ws_size,
                              hipStream_t stream) {
    const float* x    = (const float*)d_in[0];
    const float* c1   = (const float*)d_in[1];
    const float* c2   = (const float*)d_in[2];
    const float* c3   = (const float*)d_in[3];
    const float* c4   = (const float*)d_in[4];
    const float* bias = (const float*)d_in[5];
    float* out = (float*)d_out;
    short* wpb = (short*)d_ws;

    prep_all<<<29,  256, 0, stream>>>(c1, c2, c3, c4, wpb);
    tt_gemm <<<512, 512, 0, stream>>>(x, wpb, bias, out);
}

// Round 4
// 125.660 us; speedup vs baseline: 1.3426x; 1.1817x over previous
//
#include <hip/hip_runtime.h>

// TT-linear: y = x[16384,784] @ W[784,512] + bias; out = softmax(relu(y), axis=1)
// prep_all: 225 blocks build W (bf16, MFMA B-fragment layout) from TT cores.
// tt_gemm : A staged per-block in LDS (bf16, frag order), B dist-2 register
//           pipeline from L2, 8 MFMA/iter/wave, fused bias+relu+softmax.
//
// ws: [0, 819200) Wp bf16, idx = ((tn*25+tk)*64 + lane)*8 + j
//     = W[k=tk*32+quad*8+j][n=tn*16+lid]   (lane = quad*16+lid)

typedef __attribute__((ext_vector_type(8))) short short8;
typedef __attribute__((ext_vector_type(4))) float floatx4;

__device__ __forceinline__ unsigned int pack2_bf16(float a, float b) {
    unsigned int ua = __float_as_uint(a);
    unsigned int ub = __float_as_uint(b);
    return ((ub + 0x8000u) & 0xFFFF0000u) | ((ua + 0x8000u) >> 16);
}

__device__ __forceinline__ short f32_to_bf16_rne(float v) {
    unsigned int u = __float_as_uint(v);
    return (short)(((u + 0x7FFFu + ((u >> 16) & 1)) >> 16) & 0xFFFF);
}

// ---------- prep: t12 -> t123 slice -> wp slice, 225 blocks x 256 ----------
// Block b<224: ij = b>>3 (28 k-values), strip = b&7 (64 n-values).
// Block 224: zero-fill K-pad rows k in [784,800).
__global__ void prep_all(const float* __restrict__ c1, const float* __restrict__ c2,
                         const float* __restrict__ c3, const float* __restrict__ c4,
                         short* __restrict__ wp) {
    const int tid = threadIdx.x;
    const int blk = blockIdx.x;
    if (blk == 224) {                      // zero wp for k in [784,800)
        for (int e = tid; e < 8192; e += 256) {
            int j   = e & 7;
            int lid = (e >> 3) & 15;
            int q2  = (e >> 7) & 1;
            int tn  = e >> 8;
            wp[(((tn * 25 + 24) * 64 + (2 + q2) * 16 + lid) << 3) + j] = 0;
        }
        return;
    }
    __shared__ float t12s[320];            // [pq(16)][s(20)]
    __shared__ float t123s[7 * 256];       // [k3(7)][pql(16)][t(16)], pql=qloc*8+e3
    __shared__ float c4s[256];             // [t(16)][l(4)][f4(4)]

    const int ij    = blk >> 3;
    const int strip = blk & 7;
    const int i  = ij >> 2, j2 = ij & 3;
    const int p  = strip >> 1;             // n1 digit for this strip
    const int qh = strip & 1;              // q = 2*qh + qloc

    if (tid < 256) c4s[tid] = c4[tid];
    for (int e = tid; e < 320; e += 256) {
        int s = e % 20, pq = e / 20;
        int pp = pq >> 2, q = pq & 3;
        float acc = 0.f;
        #pragma unroll
        for (int r = 0; r < 20; ++r)
            acc += c1[i * 80 + pp * 20 + r] * c2[r * 320 + j2 * 80 + q * 20 + s];
        t12s[e] = acc;
    }
    __syncthreads();

    for (int e = tid; e < 1792; e += 256) {          // exactly 7 iters
        int k3 = e >> 8, li = e & 255;
        int t = li & 15, pql = li >> 4;
        int qloc = pql >> 3, e3 = pql & 7;
        int q = 2 * qh + qloc;
        float acc = 0.f;
        const float* tp = t12s + (p * 4 + q) * 20;
        const float* cp = c3 + k3 * 128 + e3 * 16 + t;
        #pragma unroll
        for (int s = 0; s < 20; ++s) acc += tp[s] * cp[s * 896];
        t123s[e] = acc;
    }
    __syncthreads();

    for (int e = tid; e < 1792; e += 256) {          // exactly 7 iters
        int kl = e >> 6, nl = e & 63;
        int k = ij * 28 + kl;
        int n = strip * 64 + nl;
        int k3 = kl >> 2, l = kl & 3;
        int f4 = n & 3, e3 = (n >> 2) & 7;
        int pql = ((n >> 5) & 1) * 8 + e3;
        const float* tp = t123s + k3 * 256 + pql * 16;
        const float* cq = c4s + l * 4 + f4;
        float a = 0.f;
        #pragma unroll
        for (int t = 0; t < 16; ++t) a += tp[t] * cq[t * 16];
        int tk = k >> 5, quad = (k >> 3) & 3, j = k & 7;
        int tn = n >> 4, lid = n & 15;
        wp[(((tn * 25 + tk) * 64 + quad * 16 + lid) << 3) + j] = f32_to_bf16_rne(a);
    }
}

// ---------- main GEMM + bias + relu + softmax ----------
// grid 512 (32 rows each), block 512 = 8 waves; wave w owns cols [w*64, w*64+64).
// A in LDS (staged once, bf16, chunk = tk*128 + mt*64 + lane).
// B: distance-2 register pipeline (3 rotating buffers), tiles 0,1 issued
// before the staging barrier so they complete during staging.
__global__ __launch_bounds__(512, 4) void tt_gemm(const float* __restrict__ x,
                                                  const short* __restrict__ wp,
                                                  const float* __restrict__ bias,
                                                  float* __restrict__ out) {
    __shared__ __align__(16) short s_a[3200 * 8];   // 51.2 KB
    __shared__ float part[8][32];

    const int tid  = threadIdx.x;
    const int w    = tid >> 6;
    const int lane = tid & 63;
    const int quad = lane >> 4;
    const int lid  = lane & 15;
    const int m_base = blockIdx.x * 32;

    const short* wpw = wp + ((size_t)(w * 4) * 25 * 64 + lane) * 8;   // tn = w*4 + nt

    // issue B tiles 0 and 1 first — they drain alongside the staging loads
    short8 b_f[3][4];
    #pragma unroll
    for (int nt = 0; nt < 4; ++nt) {
        b_f[0][nt] = *(const short8*)(wpw + (size_t)(nt * 25 + 0) * 64 * 8);
        b_f[1][nt] = *(const short8*)(wpw + (size_t)(nt * 25 + 1) * 64 * 8);
    }

    // ---- stage A: fp32 -> bf16 into LDS, chunk a = tk*128 + mt*64 + lane ----
    for (int a = tid; a < 3200; a += 512) {
        const int row = ((a >> 6) & 1) * 16 + (a & 15);          // mt*16 + lid
        const int kc  = ((a >> 7) * 4 + ((a >> 4) & 3)) * 8;     // (tk*4+quad)*8
        floatx4 v0 = {0.f, 0.f, 0.f, 0.f}, v1 = {0.f, 0.f, 0.f, 0.f};
        if (kc < 784) {
            const floatx4* pp = (const floatx4*)(x + (size_t)(m_base + row) * 784 + kc);
            v0 = pp[0]; v1 = pp[1];
        }
        union { short8 s; unsigned int u[4]; } af;
        af.u[0] = pack2_bf16(v0.x, v0.y);
        af.u[1] = pack2_bf16(v0.z, v0.w);
        af.u[2] = pack2_bf16(v1.x, v1.y);
        af.u[3] = pack2_bf16(v1.z, v1.w);
        *(short8*)&s_a[a * 8] = af.s;
    }
    __syncthreads();

    const short* sa = s_a + lane * 8;

    floatx4 acc[2][4];
    #pragma unroll
    for (int mt = 0; mt < 2; ++mt)
        #pragma unroll
        for (int nt = 0; nt < 4; ++nt)
            acc[mt][nt] = floatx4{0.f, 0.f, 0.f, 0.f};

    short8 a_f[2][2];
    a_f[0][0] = *(const short8*)(sa);
    a_f[0][1] = *(const short8*)(sa + 64 * 8);

    #pragma unroll
    for (int tk = 0; tk < 25; ++tk) {
        if (tk + 2 < 25) {                       // B prefetch, distance 2
            #pragma unroll
            for (int nt = 0; nt < 4; ++nt)
                b_f[(tk + 2) % 3][nt] = *(const short8*)(wpw + (size_t)(nt * 25 + tk + 2) * 64 * 8);
        }
        if (tk + 1 < 25) {                       // A prefetch, distance 1 (LDS)
            const short* sa2 = sa + (size_t)(tk + 1) * 128 * 8;
            a_f[(tk + 1) & 1][0] = *(const short8*)(sa2);
            a_f[(tk + 1) & 1][1] = *(const short8*)(sa2 + 64 * 8);
        }
        #pragma unroll
        for (int nt = 0; nt < 4; ++nt) {
            acc[0][nt] = __builtin_amdgcn_mfma_f32_16x16x32_bf16(a_f[tk & 1][0], b_f[tk % 3][nt], acc[0][nt], 0, 0, 0);
            acc[1][nt] = __builtin_amdgcn_mfma_f32_16x16x32_bf16(a_f[tk & 1][1], b_f[tk % 3][nt], acc[1][nt], 0, 0, 0);
        }
    }

    // ---- epilogue: bias + relu + exp, row sums across 8 waves, scale, store ----
    float bias_v[4];
    #pragma unroll
    for (int nt = 0; nt < 4; ++nt)
        bias_v[nt] = bias[w * 64 + nt * 16 + lid];

    #pragma unroll
    for (int mt = 0; mt < 2; ++mt) {
        #pragma unroll
        for (int reg = 0; reg < 4; ++reg) {
            float s = 0.f;
            #pragma unroll
            for (int nt = 0; nt < 4; ++nt) {
                float v = acc[mt][nt][reg] + bias_v[nt];
                v = fmaxf(v, 0.f);
                float e = __expf(v);
                acc[mt][nt][reg] = e;
                s += e;
            }
            s += __shfl_xor(s, 1, 64);
            s += __shfl_xor(s, 2, 64);
            s += __shfl_xor(s, 4, 64);
            s += __shfl_xor(s, 8, 64);
            if (lid == 0) part[w][mt * 16 + quad * 4 + reg] = s;
        }
    }
    __syncthreads();

    #pragma unroll
    for (int mt = 0; mt < 2; ++mt) {
        #pragma unroll
        for (int reg = 0; reg < 4; ++reg) {
            const int row = mt * 16 + quad * 4 + reg;
            float tot = 0.f;
            #pragma unroll
            for (int ww = 0; ww < 8; ++ww) tot += part[ww][row];
            const float inv = 1.0f / tot;
            #pragma unroll
            for (int nt = 0; nt < 4; ++nt)
                out[(size_t)(m_base + row) * 512 + w * 64 + nt * 16 + lid] = acc[mt][nt][reg] * inv;
        }
    }
}

extern "C" void kernel_launch(void* const* d_in, const int* in_sizes, int n_in,
                              void* d_out, int out_size, void* d_ws, size_t ws_size,
                              hipStream_t stream) {
    const float* x    = (const float*)d_in[0];
    const float* c1   = (const float*)d_in[1];
    const float* c2   = (const float*)d_in[2];
    const float* c3   = (const float*)d_in[3];
    const float* c4   = (const float*)d_in[4];
    const float* bias = (const float*)d_in[5];
    float* out = (float*)d_out;
    short* wpb = (short*)d_ws;

    prep_all<<<225, 256, 0, stream>>>(c1, c2, c3, c4, wpb);
    tt_gemm <<<512, 512, 0, stream>>>(x, wpb, bias, out);
}